// Round 5
// baseline (577.930 us; speedup 1.0000x reference)
//
#include <hip/hip_runtime.h>
#include <cmath>

// Problem constants
constexpr int Bn   = 64;
constexpr int Sn   = 8192;
constexpr int DDEC = 128;
constexpr int DENC = 128;
constexpr int Fn   = 16;
constexpr int Un   = 128;

constexpr int ROWS_PER_WAVE  = 128;   // 8 subtiles of 16 rows
constexpr int ROWS_PER_BLOCK = 512;   // 4 waves
constexpr int NSUB = ROWS_PER_WAVE / 16;

using bf16x8 = __attribute__((ext_vector_type(8))) short;
using f32x4  = __attribute__((ext_vector_type(4))) float;

__device__ __forceinline__ float fast_tanh(float x) {
    float ax = fabsf(x);
    float e  = __expf(2.0f * ax);
    float t  = 1.0f - 2.0f * __builtin_amdgcn_rcpf(e + 1.0f);
    return copysignf(t, x);
}

__device__ __forceinline__ unsigned int fkey(float f) {
    unsigned int u = __float_as_uint(f);
    return (u & 0x80000000u) ? ~u : (u | 0x80000000u);
}

__device__ __forceinline__ unsigned int bf16_rne(float f) {
    unsigned int u = __float_as_uint(f);
    return (u + 0x7FFFu + ((u >> 16) & 1u)) >> 16;
}

// Blocks 0..63: qq[b][u] = dec[b]@W1[:,u] + W1_b[u] + W2_b[u]; init sums/amax.
// Blocks 64..71: build bf16 B-fragment table for W2:
//   wftab[(n*4+c)*64 + lane] = 8 RNE-bf16 of W2[d][u], d=c*32+(lane>>4)*8+t, u=n*16+(lane&15)
__global__ void setup_kernel(const float* __restrict__ dec,
                             const float* __restrict__ W1,
                             const float* __restrict__ W1b,
                             const float* __restrict__ W2,
                             const float* __restrict__ W2b,
                             float* __restrict__ qq,
                             uint4* __restrict__ wftab,
                             float* __restrict__ sums,
                             unsigned long long* __restrict__ amax) {
    int blk = blockIdx.x, tid = threadIdx.x;
    if (blk < Bn) {
        if (tid < Un) {
            int b = blk, u = tid;
            float acc = W1b[u] + W2b[u];
            #pragma unroll 8
            for (int d = 0; d < DDEC; ++d)
                acc = fmaf(dec[b * DDEC + d], W1[d * Un + u], acc);
            qq[b * Un + u] = acc;
        }
        if (tid == 0) { sums[blk] = 0.0f; amax[blk] = 0ull; }
    } else {
        int n = blk - Bn;            // u-block 0..7
        int c = tid >> 6;            // k-chunk 0..3
        int lane = tid & 63;
        int d0 = c * 32 + (lane >> 4) * 8;
        int u  = n * 16 + (lane & 15);
        unsigned int r[8];
        #pragma unroll
        for (int t = 0; t < 8; ++t)
            r[t] = bf16_rne(W2[(d0 + t) * Un + u]);
        uint4 out;
        out.x = r[0] | (r[1] << 16);
        out.y = r[2] | (r[3] << 16);
        out.z = r[4] | (r[5] << 16);
        out.w = r[6] | (r[7] << 16);
        wftab[(n * 4 + c) * 64 + lane] = out;
    }
}

// Split 8 fp32 (two float4, k-order) into hi/lo bf16x8 fragments.
__device__ __forceinline__ void cvt_hilo(float4 a, float4 b, uint4& hi, uint4& lo) {
    unsigned int ua[8] = { __float_as_uint(a.x), __float_as_uint(a.y),
                           __float_as_uint(a.z), __float_as_uint(a.w),
                           __float_as_uint(b.x), __float_as_uint(b.y),
                           __float_as_uint(b.z), __float_as_uint(b.w) };
    float fa[8] = { a.x, a.y, a.z, a.w, b.x, b.y, b.z, b.w };
    unsigned int vl[8];
    #pragma unroll
    for (int j = 0; j < 8; ++j) {
        float hf = __uint_as_float(ua[j] & 0xFFFF0000u);
        vl[j] = __float_as_uint(fa[j] - hf);
    }
    hi.x = (ua[1] & 0xFFFF0000u) | (ua[0] >> 16);
    hi.y = (ua[3] & 0xFFFF0000u) | (ua[2] >> 16);
    hi.z = (ua[5] & 0xFFFF0000u) | (ua[4] >> 16);
    hi.w = (ua[7] & 0xFFFF0000u) | (ua[6] >> 16);
    lo.x = (vl[1] & 0xFFFF0000u) | (vl[0] >> 16);
    lo.y = (vl[3] & 0xFFFF0000u) | (vl[2] >> 16);
    lo.z = (vl[5] & 0xFFFF0000u) | (vl[4] >> 16);
    lo.w = (vl[7] & 0xFFFF0000u) | (vl[6] >> 16);
}

// MFMA score kernel, round-5: W2 fragments moved from 128 VGPRs/wave to 32 KB
// LDS/block (shared read-only across the 4 waves; staged once; read back as
// contiguous-across-lanes ds_read_b128 = conflict-free; hi+lo MFMAs share each
// B-fragment so each is read once per (n,c)). Per-wave VGPR demand drops to
// ~120 -> 3-4 waves/SIMD (vs round-4's 2 at ~255 regs), doubling latency-hiding
// TLP. Rows/wave 256 -> 128 so the 1024-block grid can fill the occupancy.
__global__ __launch_bounds__(256, 3)
void score_kernel(const float* __restrict__ enc,    // [B,S,DENC]
                  const float* __restrict__ mask,   // [B,S]
                  const float* __restrict__ qq,     // [B,U]
                  const uint4* __restrict__ wftab,  // [8][4][64]
                  const float* __restrict__ V,      // [U]
                  const float* __restrict__ Vb,     // [1]
                  float* __restrict__ logits,       // [B,S]
                  float* __restrict__ probs,        // [B,S] unnormalized
                  float* __restrict__ sums,         // [B]
                  unsigned long long* __restrict__ amax) {  // [B]
    __shared__ uint4 wlds[32 * 64];                 // 32 KB B-fragment table
    const int tid  = threadIdx.x;
    const int lane = tid & 63;
    const int wv   = tid >> 6;
    const int base = blockIdx.x * ROWS_PER_BLOCK + wv * ROWS_PER_WAVE;
    const int b    = blockIdx.x >> 4;               // 16 blocks per batch
    const int g    = lane >> 4;                     // k-group / row-quad
    const int li   = lane & 15;

    // Stage the fragment table once (contiguous copy), then it's read-only.
    #pragma unroll
    for (int it = 0; it < 8; ++it)
        wlds[tid + it * 256] = wftab[tid + it * 256];

    float qv[8], Vl[8];
    #pragma unroll
    for (int n = 0; n < 8; ++n) {
        qv[n] = qq[b * Un + n * 16 + li];
        Vl[n] = V[n * 16 + li];
    }
    const float Vbias = Vb[0];
    const bool active = (li < 4);

    __syncthreads();

    const float4* eptr = (const float4*)enc;
    float4 ebuf[8];
    {
        size_t i0 = (size_t)(base + li) * 32 + g * 2;
        #pragma unroll
        for (int c = 0; c < 4; ++c) {
            ebuf[2 * c]     = eptr[i0 + c * 8];
            ebuf[2 * c + 1] = eptr[i0 + c * 8 + 1];
        }
    }

    float psum = 0.0f;
    unsigned long long key = 0ull;

    #pragma unroll 1
    for (int st = 0; st < NSUB; ++st) {
        const int myrow = base + st * 16 + 4 * g + li;
        float mval = 0.0f;
        if (active) mval = mask[myrow];              // issued early, used late

        f32x4 acc[8];
        #pragma unroll
        for (int n = 0; n < 8; ++n)
            acc[n] = f32x4{qv[n], qv[n], qv[n], qv[n]};

        // MFMA block: per c, cvt the A pair (frees ebuf progressively), then
        // 8 x { ds_read B-frag (16B, contiguous across lanes); hi & lo MFMA }.
        #pragma unroll
        for (int c = 0; c < 4; ++c) {
            uint4 hi, lo;
            cvt_hilo(ebuf[2 * c], ebuf[2 * c + 1], hi, lo);
            bf16x8 ah = __builtin_bit_cast(bf16x8, hi);
            bf16x8 al = __builtin_bit_cast(bf16x8, lo);
            #pragma unroll
            for (int n = 0; n < 8; ++n) {
                bf16x8 bf = __builtin_bit_cast(bf16x8, wlds[(n * 4 + c) * 64 + lane]);
                acc[n] = __builtin_amdgcn_mfma_f32_16x16x32_bf16(ah, bf, acc[n], 0, 0, 0);
                acc[n] = __builtin_amdgcn_mfma_f32_16x16x32_bf16(al, bf, acc[n], 0, 0, 0);
            }
        }

        // Prefetch next subtile's A (ebuf fully dead here, before epilogue).
        if (st < NSUB - 1) {
            size_t i0 = (size_t)(base + (st + 1) * 16 + li) * 32 + g * 2;
            #pragma unroll
            for (int c = 0; c < 4; ++c) {
                ebuf[2 * c]     = eptr[i0 + c * 8];
                ebuf[2 * c + 1] = eptr[i0 + c * 8 + 1];
            }
        }

        // Epilogue: tanh + V-dot, 16-lane reduce, softmax partials.
        float pr0 = 0.0f, pr1 = 0.0f, pr2 = 0.0f, pr3 = 0.0f;
        #pragma unroll
        for (int n = 0; n < 8; ++n) {
            pr0 = fmaf(fast_tanh(acc[n][0]), Vl[n], pr0);
            pr1 = fmaf(fast_tanh(acc[n][1]), Vl[n], pr1);
            pr2 = fmaf(fast_tanh(acc[n][2]), Vl[n], pr2);
            pr3 = fmaf(fast_tanh(acc[n][3]), Vl[n], pr3);
        }
        #pragma unroll
        for (int off = 1; off < 16; off <<= 1) {
            pr0 += __shfl_xor(pr0, off);
            pr1 += __shfl_xor(pr1, off);
            pr2 += __shfl_xor(pr2, off);
            pr3 += __shfl_xor(pr3, off);
        }
        if (active) {
            float sc = (li == 0) ? pr0 : (li == 1) ? pr1 : (li == 2) ? pr2 : pr3;
            sc += Vbias;
            float l = 10.0f * fast_tanh(sc) - mval * 1e9f;
            logits[myrow] = l;
            float p = __expf(l - 10.0f);   // fixed max=10: logit<=10 always
            probs[myrow] = p;
            psum += p;
            unsigned long long k =
                ((unsigned long long)fkey(l) << 32) |
                (unsigned int)(Sn - 1 - (myrow & (Sn - 1)));
            if (k > key) key = k;
        }
    }

    #pragma unroll
    for (int off = 1; off < 64; off <<= 1) {
        psum += __shfl_xor(psum, off);
        unsigned long long ok = __shfl_xor(key, off);
        if (ok > key) key = ok;
    }
    if (lane == 0) {
        atomicAdd(&sums[b], psum);
        atomicMax(&amax[b], key);
    }
}

// Merged: blocks [0,512) normalize probs (float4); blocks [512,576) do the
// exact-argmax repair + gather for b = blk-512.
__global__ __launch_bounds__(256)
void finalize_kernel(const float* __restrict__ logits,
                     const float* __restrict__ enc,
                     const float* __restrict__ qq,
                     const float* __restrict__ W2,
                     const float* __restrict__ V,
                     const float* __restrict__ Vb,
                     const float* __restrict__ enc_in,
                     const float* __restrict__ sums,
                     const unsigned long long* __restrict__ amax,
                     float* __restrict__ probs,
                     float* __restrict__ out_idx,
                     float* __restrict__ out_gath) {
    int blk = blockIdx.x;
    int tid = threadIdx.x;
    if (blk < (Bn * Sn) / (256 * 4)) {
        int i4 = blk * 256 + tid;                   // float4 index
        int b = i4 >> 11;                           // (i4*4)>>13
        float inv = 1.0f / sums[b];
        float4* p4 = (float4*)probs;
        float4 v = p4[i4];
        v.x *= inv; v.y *= inv; v.z *= inv; v.w *= inv;
        p4[i4] = v;
        return;
    }
    int b = blk - (Bn * Sn) / (256 * 4);

    __shared__ int cnt;
    __shared__ int cand[64];
    __shared__ float red[256];
    __shared__ float bestL;
    __shared__ int bestI;
    if (tid == 0) { cnt = 0; bestL = -INFINITY; bestI = 0x7fffffff; }
    __syncthreads();

    unsigned int hk = (unsigned int)(amax[b] >> 32);
    float M = (hk & 0x80000000u) ? __uint_as_float(hk & 0x7FFFFFFFu)
                                 : __uint_as_float(~hk);
    const float* lrow = logits + (size_t)b * Sn;
    for (int s = tid; s < Sn; s += 256) {
        if (lrow[s] >= M - 0.125f) {
            int i = atomicAdd(&cnt, 1);
            if (i < 64) cand[i] = s;
        }
    }
    __syncthreads();
    int n = min(cnt, 64);
    int u = tid & 127, h = tid >> 7;

    for (int c = 0; c < n; ++c) {
        int row_s = cand[c];
        const float* erow = enc + ((size_t)b * Sn + row_s) * DENC;
        float kp = 0.0f;
        #pragma unroll 8
        for (int dd = 0; dd < 64; ++dd) {
            int d = h * 64 + dd;
            kp = fmaf(erow[d], W2[d * Un + u], kp);
        }
        red[tid] = kp;
        __syncthreads();
        if (tid < 128) {
            float kk = red[tid] + red[tid + 128] + qq[b * Un + tid];
            red[tid] = fast_tanh(kk) * V[tid];
        }
        __syncthreads();
        for (int off = 64; off > 0; off >>= 1) {
            if (tid < off) red[tid] += red[tid + off];
            __syncthreads();
        }
        if (tid == 0) {
            float sc = red[0] + Vb[0];
            float l = 10.0f * fast_tanh(sc);
            if (l > bestL || (l == bestL && row_s < bestI)) { bestL = l; bestI = row_s; }
        }
        __syncthreads();
    }

    if (tid == 0) out_idx[b] = (float)bestI;
    __syncthreads();
    if (tid < Fn) out_gath[b * Fn + tid] = enc_in[((size_t)b * Sn + bestI) * Fn + tid];
}

extern "C" void kernel_launch(void* const* d_in, const int* in_sizes, int n_in,
                              void* d_out, int out_size, void* d_ws, size_t ws_size,
                              hipStream_t stream) {
    const float* dec    = (const float*)d_in[0];  // [B,1,DDEC]
    const float* enc_in = (const float*)d_in[1];  // [B,S,F]
    const float* enc    = (const float*)d_in[2];  // [B,S,DENC]
    const float* mask   = (const float*)d_in[3];  // [B,S]
    const float* W1     = (const float*)d_in[4];  // [DDEC,U]
    const float* W1b    = (const float*)d_in[5];  // [U]
    const float* W2     = (const float*)d_in[6];  // [DENC,U]
    const float* W2b    = (const float*)d_in[7];  // [U]
    const float* V      = (const float*)d_in[8];  // [U,1]
    const float* Vb     = (const float*)d_in[9];  // [1]

    float* qq   = (float*)d_ws;                       // 8192 floats (32 KB)
    float* sums = qq + Bn * Un;                       // 64 floats
    unsigned long long* amax =
        (unsigned long long*)(sums + Bn);             // 64 u64 (byte 33024, 8-aligned)
    uint4* wftab = (uint4*)(amax + Bn);               // 32*64 uint4 (byte 33536, 16-aligned)

    float* logits = (float*)d_out;                    // [B,S]
    float* probs  = logits + (size_t)Bn * Sn;         // [B,S]
    float* oidx   = probs + (size_t)Bn * Sn;          // [B]
    float* ogath  = oidx + Bn;                        // [B,F]

    setup_kernel<<<Bn + 8, 256, 0, stream>>>(dec, W1, W1b, W2, W2b, qq, wftab, sums, amax);
    score_kernel<<<(Bn * Sn) / ROWS_PER_BLOCK, 256, 0, stream>>>(
        enc, mask, qq, wftab, V, Vb, logits, probs, sums, amax);
    finalize_kernel<<<(Bn * Sn) / (256 * 4) + Bn, 256, 0, stream>>>(
        logits, enc, qq, W2, V, Vb, enc_in, sums, amax, probs, oidx, ogath);
}